// Round 10
// baseline (131.757 us; speedup 1.0000x reference)
//
#include <hip/hip_runtime.h>
#include <hip/hip_bf16.h>

// B=16384 rows of logits[B,4096]; prototypes[4096,768]; boundaries[4096]
#define NB 16384
#define NC 4096
#define ND 768
#define NT 32              // 4096/128 tiles per dim
#define NIC 528            // NT*(NT+1)/2 upper-triangle tile pairs (symmetry)
#define CEB 2048           // CE blocks: 8 rows each (2 per wave)

// ws: [0) double nllp[2048]; [16384) float icp[528]. Fully rewritten each
// call; no atomics, no ctl state, no memsets.
#define WS_ICP 16384

// LESSON (R2/R3/R7): CE+IC single-kernel fusion failed 3x. Keep separate.
// LESSON (R8): CE is codegen-fragile; never graft tails onto it.
// LESSON (R9): ic after ce runs cache-cold (+~4us) and gload+swz staging
//   bought nothing; fin-tail saved less than those cost. Revert both.
// THIS ROUND (single concept): kill the prep stage. IC self-computes row
//   norms during fp32 staging (R2-verified internals). 3 kernels, ic first.

typedef __bf16 bf16x8 __attribute__((ext_vector_type(8)));
typedef float  f32x4  __attribute__((ext_vector_type(4)));

__device__ __forceinline__ unsigned short f2bf(float f) {
    return __builtin_bit_cast(unsigned short, __float2bfloat16(f));
}

// ---------------- IC: symmetric 128x128 Gram tiles, self-norm staging -------
// fp32 prototypes staged + converted to bf16 in padded LDS; per-row ||p||^2
// accumulated in fp32 during staging (exact), t1 kept in LDS. Off-diag tile
// pairs contribute both (i,j) and (j,i) constraint orders.
__global__ __launch_bounds__(256) void ic_kernel(const float* __restrict__ prot,
                                                 const float* __restrict__ bnd,
                                                 float* __restrict__ icp) {
    __shared__ __bf16 As[128][72];   // +8 pad: 2-way bank alias only (free)
    __shared__ __bf16 Bs[128][72];
    __shared__ float t1A[128], t1B[128];
    __shared__ float redf[4];
    const int tid = threadIdx.x;

    const int icid = blockIdx.x;
    int u = icid, bi = 0;
    while (u >= NT - bi) { u -= NT - bi; ++bi; }
    const int bj = bi + u;
    const bool diag = (bi == bj);
    const int row0 = bi * 128, col0 = bj * 128;

    const int lane = tid & 63, w = tid >> 6;
    const int fr = lane & 15, fq = lane >> 4;
    const int wrow = (w >> 1) * 64, wcol = (w & 1) * 64;

    f32x4 acc[4][4];
#pragma unroll
    for (int mi = 0; mi < 4; ++mi)
#pragma unroll
        for (int nj = 0; nj < 4; ++nj) acc[mi][nj] = (f32x4){0.f, 0.f, 0.f, 0.f};

    float ssA[8], ssB[8];
#pragma unroll
    for (int i = 0; i < 8; ++i) { ssA[i] = 0.f; ssB[i] = 0.f; }

    const float* Ap = prot + (size_t)row0 * ND;
    const float* Bp = prot + (size_t)col0 * ND;

    for (int kt = 0; kt < ND / 64; ++kt) {
#pragma unroll
        for (int s2 = 0; s2 < 8; ++s2) {
            int c = tid + 256 * s2;              // 2048 float4-chunks per tile
            int r = c >> 4, k4 = c & 15;
            float4 va = *reinterpret_cast<const float4*>(Ap + (size_t)r * ND + kt * 64 + k4 * 4);
            ssA[s2] += va.x * va.x + va.y * va.y + va.z * va.z + va.w * va.w;
            ushort4 ha; ha.x = f2bf(va.x); ha.y = f2bf(va.y); ha.z = f2bf(va.z); ha.w = f2bf(va.w);
            *reinterpret_cast<ushort4*>(&As[r][k4 * 4]) = ha;
            float4 vb = *reinterpret_cast<const float4*>(Bp + (size_t)r * ND + kt * 64 + k4 * 4);
            ssB[s2] += vb.x * vb.x + vb.y * vb.y + vb.z * vb.z + vb.w * vb.w;
            ushort4 hb; hb.x = f2bf(vb.x); hb.y = f2bf(vb.y); hb.z = f2bf(vb.z); hb.w = f2bf(vb.w);
            *reinterpret_cast<ushort4*>(&Bs[r][k4 * 4]) = hb;
        }
        __syncthreads();
#pragma unroll
        for (int ks = 0; ks < 64; ks += 32) {
            bf16x8 af[4], bfv[4];
#pragma unroll
            for (int mi = 0; mi < 4; ++mi)
                af[mi] = *reinterpret_cast<const bf16x8*>(&As[wrow + mi * 16 + fr][ks + fq * 8]);
#pragma unroll
            for (int nj = 0; nj < 4; ++nj)
                bfv[nj] = *reinterpret_cast<const bf16x8*>(&Bs[wcol + nj * 16 + fr][ks + fq * 8]);
#pragma unroll
            for (int mi = 0; mi < 4; ++mi)
#pragma unroll
                for (int nj = 0; nj < 4; ++nj)
                    acc[mi][nj] = __builtin_amdgcn_mfma_f32_16x16x32_bf16(af[mi], bfv[nj], acc[mi][nj], 0, 0, 0);
        }
        __syncthreads();
    }

    // per-row ||p||^2 (fp32 exact, accumulated during staging) -> t1 in LDS
#pragma unroll
    for (int s2 = 0; s2 < 8; ++s2) {
        float a = ssA[s2], c2 = ssB[s2];
#pragma unroll
        for (int off = 1; off < 16; off <<= 1) {
            a  += __shfl_xor(a, off);
            c2 += __shfl_xor(c2, off);
        }
        if ((tid & 15) == 0) {
            int r = s2 * 16 + (tid >> 4);
            t1A[r] = (1.f - bnd[row0 + r]) * a;
            t1B[r] = (1.f - bnd[col0 + r]) * c2;
        }
    }
    __syncthreads();

    // epilogue: tij = t1[i] + (b_j-1)*G ; off-diag pairs also add the mirror
    float t1a[16], ba1[16];
#pragma unroll
    for (int mi = 0; mi < 4; ++mi)
#pragma unroll
        for (int e = 0; e < 4; ++e) {
            int il = wrow + mi * 16 + fq * 4 + e;
            t1a[mi * 4 + e] = t1A[il];
            ba1[mi * 4 + e] = bnd[row0 + il] - 1.f;
        }
    float t1b[4], bb1[4];
#pragma unroll
    for (int nj = 0; nj < 4; ++nj) {
        int jl = wcol + nj * 16 + fr;
        t1b[nj] = t1B[jl];
        bb1[nj] = bnd[col0 + jl] - 1.f;
    }

    float sum = 0.f;
#pragma unroll
    for (int mi = 0; mi < 4; ++mi) {
#pragma unroll
        for (int nj = 0; nj < 4; ++nj) {
#pragma unroll
            for (int e = 0; e < 4; ++e) {
                float G = acc[mi][nj][e];
                float tij = t1a[mi * 4 + e] + bb1[nj] * G;     // (i in A, j in B)
                if (diag) {
                    int il = wrow + mi * 16 + fq * 4 + e;
                    int jl = wcol + nj * 16 + fr;
                    if (il != jl) sum += fmaxf(tij, 0.f);
                } else {
                    float tji = t1b[nj] + ba1[mi * 4 + e] * G; // mirrored order
                    sum += fmaxf(tij, 0.f) + fmaxf(tji, 0.f);
                }
            }
        }
    }
#pragma unroll
    for (int off = 32; off; off >>= 1) sum += __shfl_xor(sum, off);
    if (lane == 0) redf[w] = sum;
    __syncthreads();
    if (tid == 0) icp[icid] = redf[0] + redf[1] + redf[2] + redf[3];
}

// ---------------- CE: R5's proven standalone form (byte-identical) ----------
__global__ __launch_bounds__(256) void ce_kernel(const float* __restrict__ logits,
                                                 const int* __restrict__ targets,
                                                 double* __restrict__ nllp) {
    const int tid = threadIdx.x;
    const int w = tid >> 6, lane = tid & 63;
    const int b = blockIdx.x;
    float wave_nll = 0.f;
#pragma unroll
    for (int r = 0; r < 2; ++r) {
        const int row = b * 8 + w * 2 + r;
        const int t = targets[row];                               // broadcast
        const float4* rp = reinterpret_cast<const float4*>(logits + (size_t)row * NC);
        const float xt = logits[(size_t)row * NC + t];            // issued early
        float4 v[16];
#pragma unroll
        for (int k = 0; k < 16; ++k) v[k] = rp[lane + 64 * k];    // 1KB/instr coalesced
        float m = -3.4e38f;
#pragma unroll
        for (int k = 0; k < 16; ++k)
            m = fmaxf(m, fmaxf(fmaxf(v[k].x, v[k].y), fmaxf(v[k].z, v[k].w)));
#pragma unroll
        for (int off = 32; off; off >>= 1) m = fmaxf(m, __shfl_xor(m, off));
        float s = 0.f;
#pragma unroll
        for (int k = 0; k < 16; ++k)
            s += __expf(v[k].x - m) + __expf(v[k].y - m) + __expf(v[k].z - m) + __expf(v[k].w - m);
#pragma unroll
        for (int off = 32; off; off >>= 1) s += __shfl_xor(s, off);
        wave_nll += m + __logf(s) - xt;
    }
    __shared__ float wp[4];
    if (lane == 0) wp[w] = wave_nll;
    __syncthreads();
    if (tid == 0) nllp[b] = (double)((wp[0] + wp[1]) + (wp[2] + wp[3]));
}

// ---------------- finalize: deterministic ordered reduction ----------------
__global__ __launch_bounds__(1024) void fin_kernel(const double* __restrict__ nllp,
                                                   const float* __restrict__ icp,
                                                   float* __restrict__ out) {
    int tid = threadIdx.x;
    double s = nllp[tid] + nllp[tid + 1024];       // 2048 partials
    double s2 = (tid < NIC) ? (double)icp[tid] : 0.0;
#pragma unroll
    for (int off = 32; off; off >>= 1) {
        s  += __shfl_xor(s, off);
        s2 += __shfl_xor(s2, off);
    }
    __shared__ double sm[16], sm2[16];
    int w = tid >> 6, lane = tid & 63;
    if (lane == 0) { sm[w] = s; sm2[w] = s2; }
    __syncthreads();
    if (tid == 0) {
        double a = 0.0, c = 0.0;
        for (int i = 0; i < 16; ++i) { a += sm[i]; c += sm2[i]; }
        double cls = a / (double)NB;
        double ic  = c / ((double)NC * (double)(NC - 1));
        out[0] = (float)(cls + 0.05 * ic);
        out[1] = (float)cls;
        out[2] = (float)ic;
    }
}

extern "C" void kernel_launch(void* const* d_in, const int* in_sizes, int n_in,
                              void* d_out, int out_size, void* d_ws, size_t ws_size,
                              hipStream_t stream) {
    const float* logits  = (const float*)d_in[0];
    const int*   targets = (const int*)d_in[1];
    const float* prot    = (const float*)d_in[2];
    const float* bnd     = (const float*)d_in[3];
    float* out = (float*)d_out;
    char* ws = (char*)d_ws;
    double* nllp = (double*)(ws + 0);
    float* icp = (float*)(ws + WS_ICP);

    ic_kernel<<<NIC, 256, 0, stream>>>(prot, bnd, icp);
    ce_kernel<<<CEB, 256, 0, stream>>>(logits, targets, nllp);
    fin_kernel<<<1, 1024, 0, stream>>>(nllp, icp, out);
}

// Round 11
// 71.473 us; speedup vs baseline: 1.8435x; 1.8435x over previous
//
#include <hip/hip_runtime.h>
#include <hip/hip_bf16.h>

// B=16384 rows of logits[B,4096]; prototypes[4096,768]; boundaries[4096]
#define NB 16384
#define NC 4096
#define ND 768
#define NT 32              // 4096/128 tiles per dim
#define NIC 528            // NT*(NT+1)/2 upper-triangle tile pairs (symmetry)
#define CEB 2048           // CE blocks: 8 rows each (2 per wave)

// ws layout:
#define WS_NLLP 0          // double nllp[2048]
#define WS_ICP  16384      // float icp[528]
#define WS_T1   18560      // float t1[4096]
#define WS_P16  34944      // ushort P16[4096*768]

// LESSON (R2/R3/R7): CE+IC single-kernel fusion failed 3x. Keep separate.
// LESSON (R8): CE is codegen-fragile; never graft tails onto it.
// LESSON (R10): IC self-norm fp32 staging = +43us. Keep prep + PRECONV bf16.
// LESSON (R7/R10): IC is LATENCY-bound on its staging chain (MFMA floor ~2us).
// THIS ROUND: IC K-loop 2-phase pipeline — double-buffered LDS, gload_lds
//   prefetch of kt+1 overlapping MFMA of kt, ONE barrier per kt (was 2).

typedef __bf16 bf16x8 __attribute__((ext_vector_type(8)));
typedef float  f32x4  __attribute__((ext_vector_type(4)));

__device__ __forceinline__ unsigned short f2bf(float f) {
    return __builtin_bit_cast(unsigned short, __float2bfloat16(f));
}

__device__ __forceinline__ void gload16(const void* g, void* l) {
    // async global->LDS, 16B per lane; LDS dest = wave-uniform base + lane*16
    __builtin_amdgcn_global_load_lds(
        (const __attribute__((address_space(1))) unsigned int*)g,
        (__attribute__((address_space(3))) unsigned int*)l, 16, 0, 0);
}

// ---------------- prep: ||p||^2 -> t1, bf16 convert -> P16 ------------------
template<bool PRECONV>
__global__ __launch_bounds__(256) void prep_kernel(const float* __restrict__ prot,
                                                   const float* __restrict__ bnd,
                                                   float* __restrict__ t1,
                                                   unsigned short* __restrict__ P16) {
    int w = threadIdx.x >> 6;
    int lane = threadIdx.x & 63;
    int row = blockIdx.x * 4 + w;
    const float4* rp = reinterpret_cast<const float4*>(prot + (size_t)row * ND);
    float ss = 0.f;
#pragma unroll
    for (int it = 0; it < 3; ++it) {
        int idx = it * 64 + lane;            // 192 float4 per row
        float4 v = rp[idx];
        ss += v.x * v.x + v.y * v.y + v.z * v.z + v.w * v.w;
        if (PRECONV) {
            ushort4 h;
            h.x = f2bf(v.x); h.y = f2bf(v.y); h.z = f2bf(v.z); h.w = f2bf(v.w);
            *reinterpret_cast<ushort4*>(P16 + (size_t)row * ND + idx * 4) = h;
        }
    }
#pragma unroll
    for (int off = 32; off; off >>= 1) ss += __shfl_xor(ss, off);
    if (lane == 0) t1[row] = (1.f - bnd[row]) * ss;
}

// ---------------- IC: 128x128 Gram tiles, 2-phase pipelined K-loop ----------
// Double-buffered LINEAR LDS [128][64] bf16 per panel (2x32KB). Staging via
// gload_lds w=16 with pre-swizzled GLOBAL source (cb ^= row&7, R8-verified);
// ds_read applies the same XOR -> 2-way bank alias only (free). Per kt:
// STAGE(kt+1 -> buf^1) overlaps MFMA(buf); ONE barrier per kt.
template<bool PRECONV>
__global__ __launch_bounds__(256) void ic_kernel(const unsigned short* __restrict__ P16,
                                                 const float* __restrict__ prot,
                                                 const float* __restrict__ bnd,
                                                 const float* __restrict__ t1,
                                                 float* __restrict__ icp) {
    __shared__ __bf16 As[2][128][64];   // 32 KB
    __shared__ __bf16 Bs[2][128][64];   // 32 KB
    __shared__ float redf[4];
    const int tid = threadIdx.x;

    const int icid = blockIdx.x;
    int u = icid, bi = 0;
    while (u >= NT - bi) { u -= NT - bi; ++bi; }
    const int bj = bi + u;
    const bool diag = (bi == bj);
    const int row0 = bi * 128, col0 = bj * 128;

    const int lane = tid & 63, w = tid >> 6;
    const int fr = lane & 15, fq = lane >> 4;
    const int wrow = (w >> 1) * 64, wcol = (w & 1) * 64;

    char* ldsA = (char*)&As[0][0][0];
    char* ldsB = (char*)&Bs[0][0][0];
    const int BUFB = 128 * 64 * 2;      // 16 KB per panel per buffer

    f32x4 acc[4][4];
#pragma unroll
    for (int mi = 0; mi < 4; ++mi)
#pragma unroll
        for (int nj = 0; nj < 4; ++nj) acc[mi][nj] = (f32x4){0.f, 0.f, 0.f, 0.f};

    if (PRECONV) {
        // lane covers 16B at LDS (base + lane*16); source pre-swizzled
        const int rloc = lane >> 3;            // +row within 8-row stripe
        const int cbl = lane & 7;              // LDS 16B col-block
        // ---- prologue: stage kt=0 into buf 0 ----
#pragma unroll
        for (int it = 0; it < 4; ++it) {
            int base = (w * 4 + it) * 1024;
            int r = (base >> 7) + rloc;
            int cbs = cbl ^ (r & 7);
            gload16(P16 + (size_t)(row0 + r) * ND + cbs * 8, ldsA + base);
            gload16(P16 + (size_t)(col0 + r) * ND + cbs * 8, ldsB + base);
        }
        __syncthreads();
#pragma unroll
        for (int kt = 0; kt < 6; ++kt) {
            const int cur = (kt & 1) * BUFB;
            // ---- prefetch kt+1 into the other buffer (flies under MFMA) ----
            if (kt < 5) {
                const int nxt = ((kt + 1) & 1) * BUFB;
#pragma unroll
                for (int it = 0; it < 4; ++it) {
                    int base = (w * 4 + it) * 1024;
                    int r = (base >> 7) + rloc;
                    int cbs = cbl ^ (r & 7);
                    gload16(P16 + (size_t)(row0 + r) * ND + (kt + 1) * 64 + cbs * 8, ldsA + nxt + base);
                    gload16(P16 + (size_t)(col0 + r) * ND + (kt + 1) * 64 + cbs * 8, ldsB + nxt + base);
                }
            }
            // ---- MFMA on current buffer ----
#pragma unroll
            for (int ks = 0; ks < 64; ks += 32) {
                const int cb0 = fq + (ks >> 3);
                bf16x8 af[4], bfv[4];
#pragma unroll
                for (int mi = 0; mi < 4; ++mi) {
                    int r = wrow + mi * 16 + fr;
                    af[mi] = *reinterpret_cast<const bf16x8*>(ldsA + cur + r * 128 + ((cb0 ^ (r & 7)) << 4));
                }
#pragma unroll
                for (int nj = 0; nj < 4; ++nj) {
                    int r = wcol + nj * 16 + fr;
                    bfv[nj] = *reinterpret_cast<const bf16x8*>(ldsB + cur + r * 128 + ((cb0 ^ (r & 7)) << 4));
                }
#pragma unroll
                for (int mi = 0; mi < 4; ++mi)
#pragma unroll
                    for (int nj = 0; nj < 4; ++nj)
                        acc[mi][nj] = __builtin_amdgcn_mfma_f32_16x16x32_bf16(af[mi], bfv[nj], acc[mi][nj], 0, 0, 0);
            }
            __syncthreads();   // drains prefetch vmcnt + lgkm; next buf ready
        }
    } else {
        // fallback (unused when ws holds P16): synchronous fp32 staging
        for (int kt = 0; kt < 6; ++kt) {
            const int cur = (kt & 1) * BUFB;
#pragma unroll
            for (int s2 = 0; s2 < 4; ++s2) {
                int c = tid + 256 * s2;
                int r = c >> 3, cb = c & 7;
                int swz = ((cb ^ (r & 7)) << 4);
                const float4* pa = reinterpret_cast<const float4*>(prot + (size_t)(row0 + r) * ND + kt * 64 + cb * 8);
                float4 a0 = pa[0], a1 = pa[1];
                ushort4 h0, h1;
                h0.x = f2bf(a0.x); h0.y = f2bf(a0.y); h0.z = f2bf(a0.z); h0.w = f2bf(a0.w);
                h1.x = f2bf(a1.x); h1.y = f2bf(a1.y); h1.z = f2bf(a1.z); h1.w = f2bf(a1.w);
                *reinterpret_cast<ushort4*>(ldsA + cur + r * 128 + swz) = h0;
                *reinterpret_cast<ushort4*>(ldsA + cur + r * 128 + swz + 8) = h1;
                const float4* pb = reinterpret_cast<const float4*>(prot + (size_t)(col0 + r) * ND + kt * 64 + cb * 8);
                float4 b0 = pb[0], b1 = pb[1];
                ushort4 g0, g1;
                g0.x = f2bf(b0.x); g0.y = f2bf(b0.y); g0.z = f2bf(b0.z); g0.w = f2bf(b0.w);
                g1.x = f2bf(b1.x); g1.y = f2bf(b1.y); g1.z = f2bf(b1.z); g1.w = f2bf(b1.w);
                *reinterpret_cast<ushort4*>(ldsB + cur + r * 128 + swz) = g0;
                *reinterpret_cast<ushort4*>(ldsB + cur + r * 128 + swz + 8) = g1;
            }
            __syncthreads();
#pragma unroll
            for (int ks = 0; ks < 64; ks += 32) {
                const int cb0 = fq + (ks >> 3);
                bf16x8 af[4], bfv[4];
#pragma unroll
                for (int mi = 0; mi < 4; ++mi) {
                    int r = wrow + mi * 16 + fr;
                    af[mi] = *reinterpret_cast<const bf16x8*>(ldsA + cur + r * 128 + ((cb0 ^ (r & 7)) << 4));
                }
#pragma unroll
                for (int nj = 0; nj < 4; ++nj) {
                    int r = wcol + nj * 16 + fr;
                    bfv[nj] = *reinterpret_cast<const bf16x8*>(ldsB + cur + r * 128 + ((cb0 ^ (r & 7)) << 4));
                }
#pragma unroll
                for (int mi = 0; mi < 4; ++mi)
#pragma unroll
                    for (int nj = 0; nj < 4; ++nj)
                        acc[mi][nj] = __builtin_amdgcn_mfma_f32_16x16x32_bf16(af[mi], bfv[nj], acc[mi][nj], 0, 0, 0);
            }
            __syncthreads();
        }
    }

    // epilogue: tij = t1[i] + (b_j-1)*G ; off-diag pairs also add the mirror
    float t1a[16], ba1[16];
#pragma unroll
    for (int mi = 0; mi < 4; ++mi)
#pragma unroll
        for (int e = 0; e < 4; ++e) {
            int i = row0 + wrow + mi * 16 + fq * 4 + e;
            t1a[mi * 4 + e] = t1[i];
            ba1[mi * 4 + e] = bnd[i] - 1.f;
        }
    float t1b[4], bb1[4];
#pragma unroll
    for (int nj = 0; nj < 4; ++nj) {
        int j = col0 + wcol + nj * 16 + fr;
        t1b[nj] = t1[j];
        bb1[nj] = bnd[j] - 1.f;
    }

    float sum = 0.f;
#pragma unroll
    for (int mi = 0; mi < 4; ++mi) {
#pragma unroll
        for (int nj = 0; nj < 4; ++nj) {
#pragma unroll
            for (int e = 0; e < 4; ++e) {
                float G = acc[mi][nj][e];
                float tij = t1a[mi * 4 + e] + bb1[nj] * G;     // (i in A, j in B)
                if (diag) {
                    int il = wrow + mi * 16 + fq * 4 + e;
                    int jl = wcol + nj * 16 + fr;
                    if (il != jl) sum += fmaxf(tij, 0.f);
                } else {
                    float tji = t1b[nj] + ba1[mi * 4 + e] * G; // mirrored order
                    sum += fmaxf(tij, 0.f) + fmaxf(tji, 0.f);
                }
            }
        }
    }
#pragma unroll
    for (int off = 32; off; off >>= 1) sum += __shfl_xor(sum, off);
    if (lane == 0) redf[w] = sum;
    __syncthreads();
    if (tid == 0) icp[icid] = redf[0] + redf[1] + redf[2] + redf[3];
}

// ---------------- CE: R5's proven standalone form (byte-identical) ----------
__global__ __launch_bounds__(256) void ce_kernel(const float* __restrict__ logits,
                                                 const int* __restrict__ targets,
                                                 double* __restrict__ nllp) {
    const int tid = threadIdx.x;
    const int w = tid >> 6, lane = tid & 63;
    const int b = blockIdx.x;
    float wave_nll = 0.f;
#pragma unroll
    for (int r = 0; r < 2; ++r) {
        const int row = b * 8 + w * 2 + r;
        const int t = targets[row];                               // broadcast
        const float4* rp = reinterpret_cast<const float4*>(logits + (size_t)row * NC);
        const float xt = logits[(size_t)row * NC + t];            // issued early
        float4 v[16];
#pragma unroll
        for (int k = 0; k < 16; ++k) v[k] = rp[lane + 64 * k];    // 1KB/instr coalesced
        float m = -3.4e38f;
#pragma unroll
        for (int k = 0; k < 16; ++k)
            m = fmaxf(m, fmaxf(fmaxf(v[k].x, v[k].y), fmaxf(v[k].z, v[k].w)));
#pragma unroll
        for (int off = 32; off; off >>= 1) m = fmaxf(m, __shfl_xor(m, off));
        float s = 0.f;
#pragma unroll
        for (int k = 0; k < 16; ++k)
            s += __expf(v[k].x - m) + __expf(v[k].y - m) + __expf(v[k].z - m) + __expf(v[k].w - m);
#pragma unroll
        for (int off = 32; off; off >>= 1) s += __shfl_xor(s, off);
        wave_nll += m + __logf(s) - xt;
    }
    __shared__ float wp[4];
    if (lane == 0) wp[w] = wave_nll;
    __syncthreads();
    if (tid == 0) nllp[b] = (double)((wp[0] + wp[1]) + (wp[2] + wp[3]));
}

// ---------------- finalize: deterministic ordered reduction ----------------
__global__ __launch_bounds__(1024) void fin_kernel(const double* __restrict__ nllp,
                                                   const float* __restrict__ icp,
                                                   float* __restrict__ out) {
    int tid = threadIdx.x;
    double s = nllp[tid] + nllp[tid + 1024];       // 2048 partials
    double s2 = (tid < NIC) ? (double)icp[tid] : 0.0;
#pragma unroll
    for (int off = 32; off; off >>= 1) {
        s  += __shfl_xor(s, off);
        s2 += __shfl_xor(s2, off);
    }
    __shared__ double sm[16], sm2[16];
    int w = tid >> 6, lane = tid & 63;
    if (lane == 0) { sm[w] = s; sm2[w] = s2; }
    __syncthreads();
    if (tid == 0) {
        double a = 0.0, c = 0.0;
        for (int i = 0; i < 16; ++i) { a += sm[i]; c += sm2[i]; }
        double cls = a / (double)NB;
        double ic  = c / ((double)NC * (double)(NC - 1));
        out[0] = (float)(cls + 0.05 * ic);
        out[1] = (float)cls;
        out[2] = (float)ic;
    }
}

extern "C" void kernel_launch(void* const* d_in, const int* in_sizes, int n_in,
                              void* d_out, int out_size, void* d_ws, size_t ws_size,
                              hipStream_t stream) {
    const float* logits  = (const float*)d_in[0];
    const int*   targets = (const int*)d_in[1];
    const float* prot    = (const float*)d_in[2];
    const float* bnd     = (const float*)d_in[3];
    float* out = (float*)d_out;
    char* ws = (char*)d_ws;
    double* nllp = (double*)(ws + WS_NLLP);
    float* icp = (float*)(ws + WS_ICP);
    float* t1  = (float*)(ws + WS_T1);
    unsigned short* P16 = (unsigned short*)(ws + WS_P16);
    bool pre = ws_size >= (size_t)WS_P16 + 2ull * NC * ND;

    if (pre) {
        prep_kernel<true><<<NC / 4, 256, 0, stream>>>(prot, bnd, t1, P16);
        ic_kernel<true><<<NIC, 256, 0, stream>>>(P16, prot, bnd, t1, icp);
    } else {
        prep_kernel<false><<<NC / 4, 256, 0, stream>>>(prot, bnd, t1, nullptr);
        ic_kernel<false><<<NIC, 256, 0, stream>>>(nullptr, prot, bnd, t1, icp);
    }
    ce_kernel<<<CEB, 256, 0, stream>>>(logits, targets, nllp);
    fin_kernel<<<1, 1024, 0, stream>>>(nllp, icp, out);
}